// Round 3
// baseline (188.462 us; speedup 1.0000x reference)
//
#include <hip/hip_runtime.h>

typedef __bf16 bf16;
typedef __bf16 bf16x8 __attribute__((ext_vector_type(8)));
typedef float f32x4 __attribute__((ext_vector_type(4)));

#define T_LEN   4096
#define D_MODEL 1024
#define QKV_LD  1536
#define VT_LD   4128   // 4096 + 32 pad: last tile's PV chunk over-reads into pad (x0 P)
#define WINDOW  256

// async global->LDS, 16 B per lane; data lands at readfirstlane(l) + lane*16
__device__ __forceinline__ void gload_lds16(const bf16* g, bf16* l) {
    __builtin_amdgcn_global_load_lds((const __attribute__((address_space(1))) void*)g,
                                     (__attribute__((address_space(3))) void*)l, 16, 0, 0);
}

// ---------------- prep kernels ----------------

__global__ void cvt_f32_bf16(const float* __restrict__ in, bf16* __restrict__ out, int n) {
    int i = (blockIdx.x * blockDim.x + threadIdx.x) * 8;
    if (i >= n) return;
    float4 a = *(const float4*)(in + i);
    float4 b = *(const float4*)(in + i + 4);
    bf16x8 o;
    o[0] = (bf16)a.x; o[1] = (bf16)a.y; o[2] = (bf16)a.z; o[3] = (bf16)a.w;
    o[4] = (bf16)b.x; o[5] = (bf16)b.y; o[6] = (bf16)b.z; o[7] = (bf16)b.w;
    *(bf16x8*)(out + i) = o;
}

__global__ void concat_bias(const float* __restrict__ bq, const float* __restrict__ bk,
                            const float* __restrict__ bv, float* __restrict__ out) {
    int i = blockIdx.x * blockDim.x + threadIdx.x;   // grid covers exactly 1536
    if (i < 1024)      out[i] = bq[i];
    else if (i < 1280) out[i] = bk[i - 1024];
    else               out[i] = bv[i - 1280];
}

// fused Wq|Wk|Wv transpose: W (K x Nsrc, f32) cols -> WtQKV rows (1536 x 1024, bf16)
__global__ void transpose_wqkv(const float* __restrict__ Wq, const float* __restrict__ Wk,
                               const float* __restrict__ Wv, bf16* __restrict__ Wt) {
    __shared__ float t[32][33];
    int n0 = blockIdx.x * 32, k0 = blockIdx.y * 32;   // n0 in [0,1536)
    const float* W; int Ns, nofs;
    if (n0 < 1024)      { W = Wq; Ns = 1024; nofs = 0; }
    else if (n0 < 1280) { W = Wk; Ns = 256;  nofs = 1024; }
    else                { W = Wv; Ns = 256;  nofs = 1280; }
    int tx = threadIdx.x & 31, ty = threadIdx.x >> 5;
#pragma unroll
    for (int it = 0; it < 4; ++it)
        t[ty + it * 8][tx] = W[(size_t)(k0 + ty + it * 8) * Ns + (n0 - nofs) + tx];
    __syncthreads();
#pragma unroll
    for (int it = 0; it < 4; ++it)
        Wt[(size_t)(n0 + ty + it * 8) * 1024 + k0 + tx] = (bf16)t[tx][ty + it * 8];
}

// W (K x N, f32) -> Wt (N x K, bf16)
__global__ void transpose_w(const float* __restrict__ W, bf16* __restrict__ Wt, int K, int N) {
    __shared__ float t[32][33];
    int n0 = blockIdx.x * 32, k0 = blockIdx.y * 32;
    int tx = threadIdx.x & 31, ty = threadIdx.x >> 5;
#pragma unroll
    for (int it = 0; it < 4; ++it)
        t[ty + it * 8][tx] = W[(size_t)(k0 + ty + it * 8) * N + n0 + tx];
    __syncthreads();
#pragma unroll
    for (int it = 0; it < 4; ++it)
        Wt[(size_t)(n0 + ty + it * 8) * K + k0 + tx] = (bf16)t[tx][ty + it * 8];
}

// V cols of QKV (T x 1536, cols 1280..1535) -> Vt (256 x VT_LD)
__global__ void transpose_v(const bf16* __restrict__ QKV, bf16* __restrict__ Vt) {
    __shared__ bf16 t[32][33];
    int t0 = blockIdx.x * 32;   // token tile
    int c0 = blockIdx.y * 32;   // v feature tile (0..255)
    int tx = threadIdx.x & 31, ty = threadIdx.x >> 5;
#pragma unroll
    for (int it = 0; it < 4; ++it)
        t[ty + it * 8][tx] = QKV[(size_t)(t0 + ty + it * 8) * QKV_LD + 1280 + c0 + tx];
    __syncthreads();
#pragma unroll
    for (int it = 0; it < 4; ++it)
        Vt[(size_t)(c0 + ty + it * 8) * VT_LD + t0 + tx] = t[tx][ty + it * 8];
}

// ---------------- GEMM (m97 structure): C(MxN) = A(MxK)*Bt(NxK)^T + bias ----
// 128x128 tile, BK=32, 4 waves (2x2), each wave 64x64 = 4x4 MFMA tiles.
// Staging via global_load_lds width=16: LDS tiles UNPADDED [128][32] (64 B
// rows) so each wave-instruction's 64x16 B lands contiguously
// (lane*16 == (lane>>2)*64 + (lane&3)*16). 2 insts/wave for A, 2 for B.

template <bool OUT_BF16>
__global__ __launch_bounds__(256) void gemm_bt(
    const bf16* __restrict__ A, const bf16* __restrict__ Bt,
    const float* __restrict__ bias, void* __restrict__ Cv,
    int M, int N, int K)
{
    __shared__ bf16 As[128 * 32];
    __shared__ bf16 Bs[128 * 32];
    const int m0 = blockIdx.y * 128;
    const int n0 = blockIdx.x * 128;
    const int tid  = threadIdx.x;
    const int wave = tid >> 6, lane = tid & 63;
    const int quad = lane >> 4, l16 = lane & 15;
    const int wm = wave >> 1, wn = wave & 1;

    f32x4 acc[4][4] = {};

    const int srow = wave * 32 + (lane >> 2);   // staging row (t=0); +16 for t=1
    const int scol = (lane & 3) * 8;            // element offset within 32-elem row
    const bf16* ga0 = A  + (size_t)(m0 + srow) * K + scol;
    const bf16* ga1 = A  + (size_t)(m0 + srow + 16) * K + scol;
    const bf16* gb0 = Bt + (size_t)(n0 + srow) * K + scol;
    const bf16* gb1 = Bt + (size_t)(n0 + srow + 16) * K + scol;
    bf16* la0 = As + srow * 32 + scol;
    bf16* la1 = As + (srow + 16) * 32 + scol;
    bf16* lb0 = Bs + srow * 32 + scol;
    bf16* lb1 = Bs + (srow + 16) * 32 + scol;

    const int nk = K >> 5;
    for (int kt = 0; kt < nk; ++kt) {
        __syncthreads();                         // prev compute done before overwrite
        gload_lds16(ga0 + kt * 32, la0);
        gload_lds16(ga1 + kt * 32, la1);
        gload_lds16(gb0 + kt * 32, lb0);
        gload_lds16(gb1 + kt * 32, lb1);
        __syncthreads();                         // staging drained (vmcnt 0)
        bf16x8 af[4], bfr[4];
#pragma unroll
        for (int i = 0; i < 4; ++i)
            af[i] = *(const bf16x8*)&As[(wm * 64 + i * 16 + l16) * 32 + quad * 8];
#pragma unroll
        for (int j = 0; j < 4; ++j)
            bfr[j] = *(const bf16x8*)&Bs[(wn * 64 + j * 16 + l16) * 32 + quad * 8];
#pragma unroll
        for (int i = 0; i < 4; ++i)
#pragma unroll
            for (int j = 0; j < 4; ++j)
                acc[i][j] = __builtin_amdgcn_mfma_f32_16x16x32_bf16(af[i], bfr[j], acc[i][j], 0, 0, 0);
    }

#pragma unroll
    for (int i = 0; i < 4; ++i)
#pragma unroll
        for (int j = 0; j < 4; ++j) {
            const int col = n0 + wn * 64 + j * 16 + l16;
            const float bb = bias[col];
#pragma unroll
            for (int r = 0; r < 4; ++r) {
                const int row = m0 + wm * 64 + i * 16 + quad * 4 + r;
                const float v = acc[i][j][r] + bb;
                if (OUT_BF16) ((bf16*)Cv)[(size_t)row * N + col] = (bf16)v;
                else          ((float*)Cv)[(size_t)row * N + col] = v;
            }
        }
}

// ---------------- attention: 1 wave per (16-query tile, head) ----------------
// Window <= 272 keys -> 17 S tiles of 16, PV over 9 K-chunks of 32.

__global__ __launch_bounds__(64) void attn_kernel(
    const bf16* __restrict__ QKV, const bf16* __restrict__ Vt, bf16* __restrict__ Oa)
{
    __shared__ bf16 Ps[16][296];   // 592 B rows: 16B aligned, 2-way alias only
    const int q0 = blockIdx.x * 16;
    const int h  = blockIdx.y;
    const int kh = h >> 2;                     // GQA: head h -> kv head h/4
    const int lane = threadIdx.x;
    const int quad = lane >> 4, l16 = lane & 15;
    const float slope = exp2f(-0.5f * (float)(h + 1));   // NH=16 ALiBi slopes
    const int lo = (q0 >= 256) ? (q0 - 256) : 0;          // window start

    // Q A-fragments (k-chunks 0 and 32 of HD=64)
    const bf16* qp = QKV + (size_t)(q0 + l16) * QKV_LD + h * 64 + quad * 8;
    bf16x8 qf0 = *(const bf16x8*)qp;
    bf16x8 qf1 = *(const bf16x8*)(qp + 32);

    // S = Q K^T : 17 tiles of 16 keys, fully unrolled so s[] stays in VGPRs
    f32x4 s[17];
#pragma unroll
    for (int t = 0; t < 17; ++t) {
        const bf16* kp = QKV + (size_t)(lo + t * 16 + l16) * QKV_LD + D_MODEL + kh * 64 + quad * 8;
        bf16x8 kf0 = *(const bf16x8*)kp;
        bf16x8 kf1 = *(const bf16x8*)(kp + 32);
        f32x4 a = {};
        a = __builtin_amdgcn_mfma_f32_16x16x32_bf16(qf0, kf0, a, 0, 0, 0);
        a = __builtin_amdgcn_mfma_f32_16x16x32_bf16(qf1, kf1, a, 0, 0, 0);
        s[t] = a;
    }

    // masked ALiBi softmax; lane holds rows quad*4+r at col l16 of each tile
    float rinv[4];
#pragma unroll
    for (int r = 0; r < 4; ++r) {
        const int row = q0 + quad * 4 + r;
        float mx = -1e30f;
#pragma unroll
        for (int t = 0; t < 17; ++t) {
            const int key = lo + t * 16 + l16;
            float v = s[t][r] * 0.125f - slope * (float)(row - key);
            const bool ok = (key <= row) && (key > row - WINDOW);
            v = ok ? v : -1e30f;
            s[t][r] = v;
            mx = fmaxf(mx, v);
        }
#pragma unroll
        for (int d = 1; d < 16; d <<= 1) mx = fmaxf(mx, __shfl_xor(mx, d));
        float sum = 0.f;
#pragma unroll
        for (int t = 0; t < 17; ++t) {
            float p = __expf(s[t][r] - mx);
            s[t][r] = p;
            sum += p;
        }
#pragma unroll
        for (int d = 1; d < 16; d <<= 1) sum += __shfl_xor(sum, d);
        rinv[r] = 1.f / sum;
    }

    // zero pad cols [272,288) (PV reads 288 cols)
    {
        int idx = lane;
#pragma unroll
        for (int it = 0; it < 4; ++it) {
            Ps[(idx >> 4) & 15][272 + (idx & 15)] = (bf16)0.f;
            idx += 64;
        }
    }
    // P: C-layout regs -> LDS -> A-layout frags
#pragma unroll
    for (int t = 0; t < 17; ++t)
#pragma unroll
        for (int r = 0; r < 4; ++r)
            Ps[quad * 4 + r][t * 16 + l16] = (bf16)(s[t][r] * rinv[r]);
    __syncthreads();

    // O = P V : V B-frags straight from global Vt (contiguous along keys)
    f32x4 o[4] = {};
#pragma unroll
    for (int c = 0; c < 9; ++c) {
        bf16x8 pf = *(const bf16x8*)&Ps[l16][c * 32 + quad * 8];
#pragma unroll
        for (int j = 0; j < 4; ++j) {
            const bf16* vp = Vt + (size_t)(kh * 64 + j * 16 + l16) * VT_LD + lo + c * 32 + quad * 8;
            bf16x8 vf = *(const bf16x8*)vp;
            o[j] = __builtin_amdgcn_mfma_f32_16x16x32_bf16(pf, vf, o[j], 0, 0, 0);
        }
    }

#pragma unroll
    for (int j = 0; j < 4; ++j)
#pragma unroll
        for (int r = 0; r < 4; ++r)
            Oa[(size_t)(q0 + quad * 4 + r) * D_MODEL + h * 64 + j * 16 + l16] = (bf16)o[j][r];
}

// ---------------- launch ----------------

extern "C" void kernel_launch(void* const* d_in, const int* in_sizes, int n_in,
                              void* d_out, int out_size, void* d_ws, size_t ws_size,
                              hipStream_t stream) {
    const float* x  = (const float*)d_in[0];
    const float* Wq = (const float*)d_in[1];
    const float* bq = (const float*)d_in[2];
    const float* Wk = (const float*)d_in[3];
    const float* bk = (const float*)d_in[4];
    const float* Wv = (const float*)d_in[5];
    const float* bv = (const float*)d_in[6];
    const float* Wo = (const float*)d_in[7];
    const float* bo = (const float*)d_in[8];
    float* out = (float*)d_out;

    char* ws = (char*)d_ws;
    bf16*  xb    = (bf16*)(ws);                    // 4096x1024 bf16   (8 MB)
    bf16*  WtQKV = (bf16*)(ws + 8388608);          // 1536x1024 bf16   (3 MB)
    bf16*  WtO   = (bf16*)(ws + 11534336);         // 1024x1024 bf16   (2 MB)
    float* biasQ = (float*)(ws + 13631488);        // 1536 f32
    bf16*  QKV   = (bf16*)(ws + 13637632);         // 4096x1536 bf16   (12 MB)
    bf16*  Vt    = (bf16*)(ws + 26220544);         // 256xVT_LD bf16   (~2 MB)
    bf16*  AO    = (bf16*)(ws + 28334080);         // 4096x1024 bf16   (8 MB) -> end ~35 MB

    cvt_f32_bf16<<<2048, 256, 0, stream>>>(x, xb, 4096 * 1024);
    concat_bias<<<6, 256, 0, stream>>>(bq, bk, bv, biasQ);
    transpose_wqkv<<<dim3(48, 32), 256, 0, stream>>>(Wq, Wk, Wv, WtQKV);
    transpose_w<<<dim3(32, 32), 256, 0, stream>>>(Wo, WtO, 1024, 1024);

    gemm_bt<true><<<dim3(12, 32), 256, 0, stream>>>(xb, WtQKV, biasQ, QKV, 4096, 1536, 1024);
    transpose_v<<<dim3(128, 8), 256, 0, stream>>>(QKV, Vt);
    attn_kernel<<<dim3(256, 16), 64, 0, stream>>>(QKV, Vt, AO);
    gemm_bt<false><<<dim3(8, 32), 256, 0, stream>>>(AO, WtO, bo, out, 4096, 1024, 1024);
}

// Round 4
// 181.223 us; speedup vs baseline: 1.0399x; 1.0399x over previous
//
#include <hip/hip_runtime.h>

typedef __bf16 bf16;
typedef __bf16 bf16x8 __attribute__((ext_vector_type(8)));
typedef float f32x4 __attribute__((ext_vector_type(4)));

#define T_LEN   4096
#define D_MODEL 1024
#define QKV_LD  1536
#define VT_LD   4128   // 4096 + 32 pad: last tile's PV chunk over-reads into pad (x0 P)
#define WINDOW  256

// async global->LDS, 16 B per lane; data lands at readfirstlane(l) + lane*16
__device__ __forceinline__ void gload_lds16(const bf16* g, bf16* l) {
    __builtin_amdgcn_global_load_lds((const __attribute__((address_space(1))) void*)g,
                                     (__attribute__((address_space(3))) void*)l, 16, 0, 0);
}

// ---------------- prep kernels ----------------

__global__ void cvt_f32_bf16(const float* __restrict__ in, bf16* __restrict__ out, int n) {
    int i = (blockIdx.x * blockDim.x + threadIdx.x) * 8;
    if (i >= n) return;
    float4 a = *(const float4*)(in + i);
    float4 b = *(const float4*)(in + i + 4);
    bf16x8 o;
    o[0] = (bf16)a.x; o[1] = (bf16)a.y; o[2] = (bf16)a.z; o[3] = (bf16)a.w;
    o[4] = (bf16)b.x; o[5] = (bf16)b.y; o[6] = (bf16)b.z; o[7] = (bf16)b.w;
    *(bf16x8*)(out + i) = o;
}

// fused Wq|Wk|Wv transpose: W (K x Nsrc, f32) cols -> WtQKV rows (1536 x 1024, bf16)
__global__ void transpose_wqkv(const float* __restrict__ Wq, const float* __restrict__ Wk,
                               const float* __restrict__ Wv, bf16* __restrict__ Wt) {
    __shared__ float t[32][33];
    int n0 = blockIdx.x * 32, k0 = blockIdx.y * 32;   // n0 in [0,1536)
    const float* W; int Ns, nofs;
    if (n0 < 1024)      { W = Wq; Ns = 1024; nofs = 0; }
    else if (n0 < 1280) { W = Wk; Ns = 256;  nofs = 1024; }
    else                { W = Wv; Ns = 256;  nofs = 1280; }
    int tx = threadIdx.x & 31, ty = threadIdx.x >> 5;
#pragma unroll
    for (int it = 0; it < 4; ++it)
        t[ty + it * 8][tx] = W[(size_t)(k0 + ty + it * 8) * Ns + (n0 - nofs) + tx];
    __syncthreads();
#pragma unroll
    for (int it = 0; it < 4; ++it)
        Wt[(size_t)(n0 + ty + it * 8) * 1024 + k0 + tx] = (bf16)t[tx][ty + it * 8];
}

// W (K x N, f32) -> Wt (N x K, bf16)
__global__ void transpose_w(const float* __restrict__ W, bf16* __restrict__ Wt, int K, int N) {
    __shared__ float t[32][33];
    int n0 = blockIdx.x * 32, k0 = blockIdx.y * 32;
    int tx = threadIdx.x & 31, ty = threadIdx.x >> 5;
#pragma unroll
    for (int it = 0; it < 4; ++it)
        t[ty + it * 8][tx] = W[(size_t)(k0 + ty + it * 8) * N + n0 + tx];
    __syncthreads();
#pragma unroll
    for (int it = 0; it < 4; ++it)
        Wt[(size_t)(n0 + ty + it * 8) * K + k0 + tx] = (bf16)t[tx][ty + it * 8];
}

// V cols of QKV (T x 1536, cols 1280..1535) -> Vt (256 x VT_LD)
__global__ void transpose_v(const bf16* __restrict__ QKV, bf16* __restrict__ Vt) {
    __shared__ bf16 t[32][33];
    int t0 = blockIdx.x * 32;   // token tile
    int c0 = blockIdx.y * 32;   // v feature tile (0..255)
    int tx = threadIdx.x & 31, ty = threadIdx.x >> 5;
#pragma unroll
    for (int it = 0; it < 4; ++it)
        t[ty + it * 8][tx] = QKV[(size_t)(t0 + ty + it * 8) * QKV_LD + 1280 + c0 + tx];
    __syncthreads();
#pragma unroll
    for (int it = 0; it < 4; ++it)
        Vt[(size_t)(c0 + ty + it * 8) * VT_LD + t0 + tx] = t[tx][ty + it * 8];
}

// ---------------- GEMM: C(MxN) = A(MxK)*Bt(NxK)^T + bias ----------------
// 128x64 tile, BK=32, 4 waves (2x2), each wave 64x32 = 4x2 MFMA tiles.
// Small tile => gemm1 768 blocks (3/CU), gemm2 512 (2/CU): implicit
// cross-block overlap hides the 2-barrier staging stall (m114/m102).
// Staging via global_load_lds w16, unpadded LDS rows (64 B):
//   A: 8 KB = 2 insts/thread (rows srow, srow+64); B: 4 KB = 1 inst/thread.

template <bool OUT_BF16, bool QKV_BIAS>
__global__ __launch_bounds__(256) void gemm_bt(
    const bf16* __restrict__ A, const bf16* __restrict__ Bt,
    const float* __restrict__ b0, const float* __restrict__ b1,
    const float* __restrict__ b2, void* __restrict__ Cv,
    int M, int N, int K)
{
    __shared__ bf16 As[128 * 32];
    __shared__ bf16 Bs[64 * 32];
    const int m0 = blockIdx.y * 128;
    const int n0 = blockIdx.x * 64;
    const int tid  = threadIdx.x;
    const int wave = tid >> 6, lane = tid & 63;
    const int quad = lane >> 4, l16 = lane & 15;
    const int wm = wave >> 1, wn = wave & 1;

    f32x4 acc[4][2] = {};

    const int srow = wave * 16 + (lane >> 2);   // 0..63
    const int scol = (lane & 3) * 8;            // element offset in 32-elem row
    const bf16* ga0 = A  + (size_t)(m0 + srow) * K + scol;
    const bf16* ga1 = A  + (size_t)(m0 + srow + 64) * K + scol;
    const bf16* gb  = Bt + (size_t)(n0 + srow) * K + scol;
    bf16* la0 = As + srow * 32 + scol;
    bf16* la1 = As + (srow + 64) * 32 + scol;
    bf16* lb  = Bs + srow * 32 + scol;

    const int nk = K >> 5;
    for (int kt = 0; kt < nk; ++kt) {
        __syncthreads();                         // prev compute done before overwrite
        gload_lds16(ga0 + kt * 32, la0);
        gload_lds16(ga1 + kt * 32, la1);
        gload_lds16(gb  + kt * 32, lb);
        __syncthreads();                         // staging drained (vmcnt 0)
        bf16x8 af[4], bfr[2];
#pragma unroll
        for (int i = 0; i < 4; ++i)
            af[i] = *(const bf16x8*)&As[(wm * 64 + i * 16 + l16) * 32 + quad * 8];
#pragma unroll
        for (int j = 0; j < 2; ++j)
            bfr[j] = *(const bf16x8*)&Bs[(wn * 32 + j * 16 + l16) * 32 + quad * 8];
#pragma unroll
        for (int i = 0; i < 4; ++i)
#pragma unroll
            for (int j = 0; j < 2; ++j)
                acc[i][j] = __builtin_amdgcn_mfma_f32_16x16x32_bf16(af[i], bfr[j], acc[i][j], 0, 0, 0);
    }

#pragma unroll
    for (int i = 0; i < 4; ++i)
#pragma unroll
        for (int j = 0; j < 2; ++j) {
            const int col = n0 + wn * 32 + j * 16 + l16;
            const float bb = QKV_BIAS
                ? (col < 1024 ? b0[col] : (col < 1280 ? b1[col - 1024] : b2[col - 1280]))
                : b0[col];
#pragma unroll
            for (int r = 0; r < 4; ++r) {
                const int row = m0 + wm * 64 + i * 16 + quad * 4 + r;
                const float v = acc[i][j][r] + bb;
                if (OUT_BF16) ((bf16*)Cv)[(size_t)row * N + col] = (bf16)v;
                else          ((float*)Cv)[(size_t)row * N + col] = v;
            }
        }
}

// ---------------- attention: 4 waves/block, 1 wave per (16-query tile, head) --
// Window <= 272 keys -> 17 S tiles of 16, PV over 9 K-chunks of 32.
// Waves of a block: 4 adjacent q-tiles, same head (overlapping K windows -> L1).

__global__ __launch_bounds__(256) void attn_kernel(
    const bf16* __restrict__ QKV, const bf16* __restrict__ Vt, bf16* __restrict__ Oa)
{
    __shared__ bf16 Ps[4][16][296];   // per-wave P tile; 592 B rows: 2-way alias only
    const int wave = threadIdx.x >> 6;
    const int lane = threadIdx.x & 63;
    const int q0 = (blockIdx.x * 4 + wave) * 16;
    const int h  = blockIdx.y;
    const int kh = h >> 2;                     // GQA: head h -> kv head h/4
    const int quad = lane >> 4, l16 = lane & 15;
    const float slope = exp2f(-0.5f * (float)(h + 1));   // NH=16 ALiBi slopes
    const int lo = (q0 >= 256) ? (q0 - 256) : 0;          // window start

    // Q A-fragments (k-chunks 0 and 32 of HD=64)
    const bf16* qp = QKV + (size_t)(q0 + l16) * QKV_LD + h * 64 + quad * 8;
    bf16x8 qf0 = *(const bf16x8*)qp;
    bf16x8 qf1 = *(const bf16x8*)(qp + 32);

    // S = Q K^T : 17 tiles of 16 keys, fully unrolled so s[] stays in VGPRs
    f32x4 s[17];
#pragma unroll
    for (int t = 0; t < 17; ++t) {
        const bf16* kp = QKV + (size_t)(lo + t * 16 + l16) * QKV_LD + D_MODEL + kh * 64 + quad * 8;
        bf16x8 kf0 = *(const bf16x8*)kp;
        bf16x8 kf1 = *(const bf16x8*)(kp + 32);
        f32x4 a = {};
        a = __builtin_amdgcn_mfma_f32_16x16x32_bf16(qf0, kf0, a, 0, 0, 0);
        a = __builtin_amdgcn_mfma_f32_16x16x32_bf16(qf1, kf1, a, 0, 0, 0);
        s[t] = a;
    }

    // masked ALiBi softmax; lane holds rows quad*4+r at col l16 of each tile
    float rinv[4];
#pragma unroll
    for (int r = 0; r < 4; ++r) {
        const int row = q0 + quad * 4 + r;
        float mx = -1e30f;
#pragma unroll
        for (int t = 0; t < 17; ++t) {
            const int key = lo + t * 16 + l16;
            float v = s[t][r] * 0.125f - slope * (float)(row - key);
            const bool ok = (key <= row) && (key > row - WINDOW);
            v = ok ? v : -1e30f;
            s[t][r] = v;
            mx = fmaxf(mx, v);
        }
#pragma unroll
        for (int d = 1; d < 16; d <<= 1) mx = fmaxf(mx, __shfl_xor(mx, d));
        float sum = 0.f;
#pragma unroll
        for (int t = 0; t < 17; ++t) {
            float p = __expf(s[t][r] - mx);
            s[t][r] = p;
            sum += p;
        }
#pragma unroll
        for (int d = 1; d < 16; d <<= 1) sum += __shfl_xor(sum, d);
        rinv[r] = 1.f / sum;
    }

    // zero pad cols [272,288) (PV reads 288 cols)
    {
        int idx = lane;
#pragma unroll
        for (int it = 0; it < 4; ++it) {
            Ps[wave][(idx >> 4) & 15][272 + (idx & 15)] = (bf16)0.f;
            idx += 64;
        }
    }
    // P: C-layout regs -> LDS -> A-layout frags
#pragma unroll
    for (int t = 0; t < 17; ++t)
#pragma unroll
        for (int r = 0; r < 4; ++r)
            Ps[wave][quad * 4 + r][t * 16 + l16] = (bf16)(s[t][r] * rinv[r]);
    __syncthreads();

    // O = P V : V B-frags straight from global Vt (contiguous along keys)
    f32x4 o[4] = {};
#pragma unroll
    for (int c = 0; c < 9; ++c) {
        bf16x8 pf = *(const bf16x8*)&Ps[wave][l16][c * 32 + quad * 8];
#pragma unroll
        for (int j = 0; j < 4; ++j) {
            const bf16* vp = Vt + (size_t)(kh * 64 + j * 16 + l16) * VT_LD + lo + c * 32 + quad * 8;
            bf16x8 vf = *(const bf16x8*)vp;
            o[j] = __builtin_amdgcn_mfma_f32_16x16x32_bf16(pf, vf, o[j], 0, 0, 0);
        }
    }

#pragma unroll
    for (int j = 0; j < 4; ++j)
#pragma unroll
        for (int r = 0; r < 4; ++r)
            Oa[(size_t)(q0 + quad * 4 + r) * D_MODEL + h * 64 + j * 16 + l16] = (bf16)o[j][r];
}

// ---------------- launch ----------------

extern "C" void kernel_launch(void* const* d_in, const int* in_sizes, int n_in,
                              void* d_out, int out_size, void* d_ws, size_t ws_size,
                              hipStream_t stream) {
    const float* x  = (const float*)d_in[0];
    const float* Wq = (const float*)d_in[1];
    const float* bq = (const float*)d_in[2];
    const float* Wk = (const float*)d_in[3];
    const float* bk = (const float*)d_in[4];
    const float* Wv = (const float*)d_in[5];
    const float* bv = (const float*)d_in[6];
    const float* Wo = (const float*)d_in[7];
    const float* bo = (const float*)d_in[8];
    float* out = (float*)d_out;

    char* ws = (char*)d_ws;
    bf16*  xb    = (bf16*)(ws);                    // 4096x1024 bf16   (8 MB)
    bf16*  WtQKV = (bf16*)(ws + 8388608);          // 1536x1024 bf16   (3 MB)
    bf16*  WtO   = (bf16*)(ws + 11534336);         // 1024x1024 bf16   (2 MB)
    bf16*  QKV   = (bf16*)(ws + 13637632);         // 4096x1536 bf16   (12 MB)
    bf16*  Vt    = (bf16*)(ws + 26220544);         // 256xVT_LD bf16   (~2 MB)
    bf16*  AO    = (bf16*)(ws + 28334080);         // 4096x1024 bf16   (8 MB) -> end ~35 MB

    cvt_f32_bf16<<<2048, 256, 0, stream>>>(x, xb, 4096 * 1024);
    transpose_wqkv<<<dim3(48, 32), 256, 0, stream>>>(Wq, Wk, Wv, WtQKV);
    transpose_w<<<dim3(32, 32), 256, 0, stream>>>(Wo, WtO, 1024, 1024);

    gemm_bt<true, true><<<dim3(24, 32), 256, 0, stream>>>(xb, WtQKV, bq, bk, bv, QKV, 4096, 1536, 1024);
    transpose_v<<<dim3(128, 8), 256, 0, stream>>>(QKV, Vt);
    attn_kernel<<<dim3(64, 16), 256, 0, stream>>>(QKV, Vt, AO);
    gemm_bt<false, false><<<dim3(16, 32), 256, 0, stream>>>(AO, WtO, bo, nullptr, nullptr, out, 4096, 1024, 1024);
}

// Round 5
// 172.912 us; speedup vs baseline: 1.0899x; 1.0481x over previous
//
#include <hip/hip_runtime.h>

typedef __bf16 bf16;
typedef __bf16 bf16x4 __attribute__((ext_vector_type(4)));
typedef __bf16 bf16x8 __attribute__((ext_vector_type(8)));
typedef float f32x4 __attribute__((ext_vector_type(4)));

#define T_LEN   4096
#define D_MODEL 1024
#define QKV_LD  1536
#define VT_LD   4128   // 4096 + 32 pad: last tile's PV chunk over-reads into pad (x0 P)
#define WINDOW  256

// async global->LDS, 16 B per lane; data lands at readfirstlane(l) + lane*16
__device__ __forceinline__ void gload_lds16(const bf16* g, bf16* l) {
    __builtin_amdgcn_global_load_lds((const __attribute__((address_space(1))) void*)g,
                                     (__attribute__((address_space(3))) void*)l, 16, 0, 0);
}

// ---------------- fused prep: x->bf16, Wq|Wk|Wv transpose, Wo transpose -----
// grid sections: [0,2048) cvt, [2048,3584) wqkv, [3584,4608) wo

__global__ __launch_bounds__(256) void prep_fused(
    const float* __restrict__ x,
    const float* __restrict__ Wq, const float* __restrict__ Wk,
    const float* __restrict__ Wv, const float* __restrict__ Wo,
    bf16* __restrict__ xb, bf16* __restrict__ WtQKV, bf16* __restrict__ WtO)
{
    __shared__ float t[32][33];
    const int blk = blockIdx.x;
    if (blk < 2048) {                       // ---- x (f32) -> xb (bf16)
        int i = (blk * 256 + threadIdx.x) * 8;
        float4 a = *(const float4*)(x + i);
        float4 b = *(const float4*)(x + i + 4);
        bf16x8 o;
        o[0] = (bf16)a.x; o[1] = (bf16)a.y; o[2] = (bf16)a.z; o[3] = (bf16)a.w;
        o[4] = (bf16)b.x; o[5] = (bf16)b.y; o[6] = (bf16)b.z; o[7] = (bf16)b.w;
        *(bf16x8*)(xb + i) = o;
        return;
    }
    const float* W; bf16* Wt; int n0, k0, Ns, nofs;
    if (blk < 3584) {                       // ---- Wq|Wk|Wv -> WtQKV (1536x1024)
        int b = blk - 2048;
        n0 = (b % 48) * 32; k0 = (b / 48) * 32;
        if (n0 < 1024)      { W = Wq; Ns = 1024; nofs = 0; }
        else if (n0 < 1280) { W = Wk; Ns = 256;  nofs = 1024; }
        else                { W = Wv; Ns = 256;  nofs = 1280; }
        Wt = WtQKV;
    } else {                                // ---- Wo -> WtO (1024x1024)
        int b = blk - 3584;
        n0 = (b % 32) * 32; k0 = (b / 32) * 32;
        W = Wo; Ns = 1024; nofs = 0; Wt = WtO;
    }
    int tx = threadIdx.x & 31, ty = threadIdx.x >> 5;
#pragma unroll
    for (int it = 0; it < 4; ++it)
        t[ty + it * 8][tx] = W[(size_t)(k0 + ty + it * 8) * Ns + (n0 - nofs) + tx];
    __syncthreads();
#pragma unroll
    for (int it = 0; it < 4; ++it)
        Wt[(size_t)(n0 + ty + it * 8) * 1024 + k0 + tx] = (bf16)t[tx][ty + it * 8];
}

// ---------------- GEMM: C(MxN) = A(MxK)*Bt(NxK)^T + bias ----------------
// 128x64 tile, BK=32, 4 waves (2x2), wave 64x32 = 4x2 MFMA tiles.
// Linear grid + XCD swizzle: blk%8 = XCD (HW round-robin heuristic); each XCD
// owns bands_per_xcd M-bands, so a band's A-slice (256 KB) stays in its 4 MB
// XCD L2 across all nbx column-blocks, and B (<=3 MB) is L2-resident too.
// QKV_BIAS path: column-blocks n0>=1280 are V -> written TRANSPOSED to Vt
// (C-layout: lane's 4 acc values = 4 consecutive tokens at fixed feature
// = one 8 B store), V region of QKV is never materialized.

template <bool OUT_BF16, bool QKV_BIAS>
__global__ __launch_bounds__(256) void gemm_bt(
    const bf16* __restrict__ A, const bf16* __restrict__ Bt,
    const float* __restrict__ b0, const float* __restrict__ b1,
    const float* __restrict__ b2, void* __restrict__ Cv, bf16* __restrict__ Vt,
    int M, int N, int K, int nbx, int bands_per_xcd)
{
    __shared__ bf16 As[128 * 32];
    __shared__ bf16 Bs[64 * 32];
    const int blk = blockIdx.x;
    const int xcd = blk & 7;
    const int s   = blk >> 3;
    const int m0 = (xcd * bands_per_xcd + s / nbx) * 128;
    const int n0 = (s % nbx) * 64;
    const int tid  = threadIdx.x;
    const int wave = tid >> 6, lane = tid & 63;
    const int quad = lane >> 4, l16 = lane & 15;
    const int wm = wave >> 1, wn = wave & 1;

    f32x4 acc[4][2] = {};

    const int srow = wave * 16 + (lane >> 2);   // 0..63
    const int scol = (lane & 3) * 8;            // element offset in 32-elem row
    const bf16* ga0 = A  + (size_t)(m0 + srow) * K + scol;
    const bf16* ga1 = A  + (size_t)(m0 + srow + 64) * K + scol;
    const bf16* gb  = Bt + (size_t)(n0 + srow) * K + scol;
    bf16* la0 = As + srow * 32 + scol;
    bf16* la1 = As + (srow + 64) * 32 + scol;
    bf16* lb  = Bs + srow * 32 + scol;

    const int nk = K >> 5;
    for (int kt = 0; kt < nk; ++kt) {
        __syncthreads();                         // prev compute done before overwrite
        gload_lds16(ga0 + kt * 32, la0);
        gload_lds16(ga1 + kt * 32, la1);
        gload_lds16(gb  + kt * 32, lb);
        __syncthreads();                         // staging drained (vmcnt 0)
        bf16x8 af[4], bfr[2];
#pragma unroll
        for (int i = 0; i < 4; ++i)
            af[i] = *(const bf16x8*)&As[(wm * 64 + i * 16 + l16) * 32 + quad * 8];
#pragma unroll
        for (int j = 0; j < 2; ++j)
            bfr[j] = *(const bf16x8*)&Bs[(wn * 32 + j * 16 + l16) * 32 + quad * 8];
#pragma unroll
        for (int i = 0; i < 4; ++i)
#pragma unroll
            for (int j = 0; j < 2; ++j)
                acc[i][j] = __builtin_amdgcn_mfma_f32_16x16x32_bf16(af[i], bfr[j], acc[i][j], 0, 0, 0);
    }

    const bool vtile = QKV_BIAS && (n0 >= 1280);
#pragma unroll
    for (int i = 0; i < 4; ++i)
#pragma unroll
        for (int j = 0; j < 2; ++j) {
            const int col = n0 + wn * 32 + j * 16 + l16;
            const float bb = QKV_BIAS
                ? (col < 1024 ? b0[col] : (col < 1280 ? b1[col - 1024] : b2[col - 1280]))
                : b0[col];
            const int row0 = m0 + wm * 64 + i * 16 + quad * 4;
            if (vtile) {
                bf16x4 pv;
#pragma unroll
                for (int r = 0; r < 4; ++r) pv[r] = (bf16)(acc[i][j][r] + bb);
                *(bf16x4*)&Vt[(size_t)(col - 1280) * VT_LD + row0] = pv;
            } else {
#pragma unroll
                for (int r = 0; r < 4; ++r) {
                    const float v = acc[i][j][r] + bb;
                    if (OUT_BF16) ((bf16*)Cv)[(size_t)(row0 + r) * N + col] = (bf16)v;
                    else          ((float*)Cv)[(size_t)(row0 + r) * N + col] = v;
                }
            }
        }
}

// ---------------- attention: 4 waves/block, 1 wave per (16-query tile, head) --
// Window <= 272 keys -> 17 S tiles of 16, PV over 9 K-chunks of 32.

__global__ __launch_bounds__(256) void attn_kernel(
    const bf16* __restrict__ QKV, const bf16* __restrict__ Vt, bf16* __restrict__ Oa)
{
    __shared__ bf16 Ps[4][16][296];   // per-wave P tile; 592 B rows: 2-way alias only
    const int wave = threadIdx.x >> 6;
    const int lane = threadIdx.x & 63;
    const int q0 = (blockIdx.x * 4 + wave) * 16;
    const int h  = blockIdx.y;
    const int kh = h >> 2;                     // GQA: head h -> kv head h/4
    const int quad = lane >> 4, l16 = lane & 15;
    const float slope = exp2f(-0.5f * (float)(h + 1));   // NH=16 ALiBi slopes
    const int lo = (q0 >= 256) ? (q0 - 256) : 0;          // window start

    // Q A-fragments (k-chunks 0 and 32 of HD=64)
    const bf16* qp = QKV + (size_t)(q0 + l16) * QKV_LD + h * 64 + quad * 8;
    bf16x8 qf0 = *(const bf16x8*)qp;
    bf16x8 qf1 = *(const bf16x8*)(qp + 32);

    // S = Q K^T : 17 tiles of 16 keys, fully unrolled so s[] stays in VGPRs
    f32x4 s[17];
#pragma unroll
    for (int t = 0; t < 17; ++t) {
        const bf16* kp = QKV + (size_t)(lo + t * 16 + l16) * QKV_LD + D_MODEL + kh * 64 + quad * 8;
        bf16x8 kf0 = *(const bf16x8*)kp;
        bf16x8 kf1 = *(const bf16x8*)(kp + 32);
        f32x4 a = {};
        a = __builtin_amdgcn_mfma_f32_16x16x32_bf16(qf0, kf0, a, 0, 0, 0);
        a = __builtin_amdgcn_mfma_f32_16x16x32_bf16(qf1, kf1, a, 0, 0, 0);
        s[t] = a;
    }

    // masked ALiBi softmax; lane holds rows quad*4+r at col l16 of each tile
    float rinv[4];
#pragma unroll
    for (int r = 0; r < 4; ++r) {
        const int row = q0 + quad * 4 + r;
        float mx = -1e30f;
#pragma unroll
        for (int t = 0; t < 17; ++t) {
            const int key = lo + t * 16 + l16;
            float v = s[t][r] * 0.125f - slope * (float)(row - key);
            const bool ok = (key <= row) && (key > row - WINDOW);
            v = ok ? v : -1e30f;
            s[t][r] = v;
            mx = fmaxf(mx, v);
        }
#pragma unroll
        for (int d = 1; d < 16; d <<= 1) mx = fmaxf(mx, __shfl_xor(mx, d));
        float sum = 0.f;
#pragma unroll
        for (int t = 0; t < 17; ++t) {
            float p = __expf(s[t][r] - mx);
            s[t][r] = p;
            sum += p;
        }
#pragma unroll
        for (int d = 1; d < 16; d <<= 1) sum += __shfl_xor(sum, d);
        rinv[r] = 1.f / sum;
    }

    // zero pad cols [272,288) (PV reads 288 cols)
    {
        int idx = lane;
#pragma unroll
        for (int it = 0; it < 4; ++it) {
            Ps[wave][(idx >> 4) & 15][272 + (idx & 15)] = (bf16)0.f;
            idx += 64;
        }
    }
    // P: C-layout regs -> LDS -> A-layout frags
#pragma unroll
    for (int t = 0; t < 17; ++t)
#pragma unroll
        for (int r = 0; r < 4; ++r)
            Ps[wave][quad * 4 + r][t * 16 + l16] = (bf16)(s[t][r] * rinv[r]);
    __syncthreads();

    // O = P V : V B-frags straight from global Vt (contiguous along keys)
    f32x4 o[4] = {};
#pragma unroll
    for (int c = 0; c < 9; ++c) {
        bf16x8 pf = *(const bf16x8*)&Ps[wave][l16][c * 32 + quad * 8];
#pragma unroll
        for (int j = 0; j < 4; ++j) {
            const bf16* vp = Vt + (size_t)(kh * 64 + j * 16 + l16) * VT_LD + lo + c * 32 + quad * 8;
            bf16x8 vf = *(const bf16x8*)vp;
            o[j] = __builtin_amdgcn_mfma_f32_16x16x32_bf16(pf, vf, o[j], 0, 0, 0);
        }
    }

#pragma unroll
    for (int j = 0; j < 4; ++j)
#pragma unroll
        for (int r = 0; r < 4; ++r)
            Oa[(size_t)(q0 + quad * 4 + r) * D_MODEL + h * 64 + j * 16 + l16] = (bf16)o[j][r];
}

// ---------------- launch ----------------

extern "C" void kernel_launch(void* const* d_in, const int* in_sizes, int n_in,
                              void* d_out, int out_size, void* d_ws, size_t ws_size,
                              hipStream_t stream) {
    const float* x  = (const float*)d_in[0];
    const float* Wq = (const float*)d_in[1];
    const float* bq = (const float*)d_in[2];
    const float* Wk = (const float*)d_in[3];
    const float* bk = (const float*)d_in[4];
    const float* Wv = (const float*)d_in[5];
    const float* bv = (const float*)d_in[6];
    const float* Wo = (const float*)d_in[7];
    const float* bo = (const float*)d_in[8];
    float* out = (float*)d_out;

    char* ws = (char*)d_ws;
    bf16*  xb    = (bf16*)(ws);                    // 4096x1024 bf16   (8 MB)
    bf16*  WtQKV = (bf16*)(ws + 8388608);          // 1536x1024 bf16   (3 MB)
    bf16*  WtO   = (bf16*)(ws + 11534336);         // 1024x1024 bf16   (2 MB)
    bf16*  QKV   = (bf16*)(ws + 13637632);         // 4096x1536 bf16   (12 MB; V region unused)
    bf16*  Vt    = (bf16*)(ws + 26220544);         // 256xVT_LD bf16   (~2 MB)
    bf16*  AO    = (bf16*)(ws + 28334080);         // 4096x1024 bf16   (8 MB) -> end ~35 MB

    prep_fused<<<4608, 256, 0, stream>>>(x, Wq, Wk, Wv, Wo, xb, WtQKV, WtO);

    gemm_bt<true, true><<<768, 256, 0, stream>>>(
        xb, WtQKV, bq, bk, bv, QKV, Vt, 4096, 1536, 1024, 24, 4);

    attn_kernel<<<dim3(64, 16), 256, 0, stream>>>(QKV, Vt, AO);

    gemm_bt<false, false><<<512, 256, 0, stream>>>(
        AO, WtO, bo, nullptr, nullptr, out, nullptr, 4096, 1024, 1024, 16, 4);
}

// Round 6
// 172.146 us; speedup vs baseline: 1.0948x; 1.0045x over previous
//
#include <hip/hip_runtime.h>

typedef __bf16 bf16;
typedef __bf16 bf16x4 __attribute__((ext_vector_type(4)));
typedef __bf16 bf16x8 __attribute__((ext_vector_type(8)));
typedef float f32x4 __attribute__((ext_vector_type(4)));

#define T_LEN   4096
#define D_MODEL 1024
#define QKV_LD  1536
#define VT_LD   4128   // 4096 + 32 pad: last tile's PV chunk over-reads into pad (x0 P)
#define WINDOW  256

// async global->LDS, 16 B per lane; data lands at readfirstlane(l) + lane*16
__device__ __forceinline__ void gload_lds16(const bf16* g, bf16* l) {
    __builtin_amdgcn_global_load_lds((const __attribute__((address_space(1))) void*)g,
                                     (__attribute__((address_space(3))) void*)l, 16, 0, 0);
}

// ---------------- fused prep: x->bf16, Wq|Wk|Wv transpose, Wo transpose -----
// grid sections: [0,2048) cvt, [2048,3584) wqkv, [3584,4608) wo

__global__ __launch_bounds__(256) void prep_fused(
    const float* __restrict__ x,
    const float* __restrict__ Wq, const float* __restrict__ Wk,
    const float* __restrict__ Wv, const float* __restrict__ Wo,
    bf16* __restrict__ xb, bf16* __restrict__ WtQKV, bf16* __restrict__ WtO)
{
    __shared__ float t[32][33];
    const int blk = blockIdx.x;
    if (blk < 2048) {                       // ---- x (f32) -> xb (bf16)
        int i = (blk * 256 + threadIdx.x) * 8;
        float4 a = *(const float4*)(x + i);
        float4 b = *(const float4*)(x + i + 4);
        bf16x8 o;
        o[0] = (bf16)a.x; o[1] = (bf16)a.y; o[2] = (bf16)a.z; o[3] = (bf16)a.w;
        o[4] = (bf16)b.x; o[5] = (bf16)b.y; o[6] = (bf16)b.z; o[7] = (bf16)b.w;
        *(bf16x8*)(xb + i) = o;
        return;
    }
    const float* W; bf16* Wt; int n0, k0, Ns, nofs;
    if (blk < 3584) {                       // ---- Wq|Wk|Wv -> WtQKV (1536x1024)
        int b = blk - 2048;
        n0 = (b % 48) * 32; k0 = (b / 48) * 32;
        if (n0 < 1024)      { W = Wq; Ns = 1024; nofs = 0; }
        else if (n0 < 1280) { W = Wk; Ns = 256;  nofs = 1024; }
        else                { W = Wv; Ns = 256;  nofs = 1280; }
        Wt = WtQKV;
    } else {                                // ---- Wo -> WtO (1024x1024)
        int b = blk - 3584;
        n0 = (b % 32) * 32; k0 = (b / 32) * 32;
        W = Wo; Ns = 1024; nofs = 0; Wt = WtO;
    }
    int tx = threadIdx.x & 31, ty = threadIdx.x >> 5;
#pragma unroll
    for (int it = 0; it < 4; ++it)
        t[ty + it * 8][tx] = W[(size_t)(k0 + ty + it * 8) * Ns + (n0 - nofs) + tx];
    __syncthreads();
#pragma unroll
    for (int it = 0; it < 4; ++it)
        Wt[(size_t)(n0 + ty + it * 8) * 1024 + k0 + tx] = (bf16)t[tx][ty + it * 8];
}

// ---------------- GEMM: C(MxN) = A(MxK)*Bt(NxK)^T + bias ----------------
// 128x64 tile, BK=32, 4 waves (2x2), wave 64x32 = 4x2 MFMA tiles.
// 3-buffer LDS pipeline, ONE raw s_barrier per K-iter, explicit partial
// vmcnt waits (inline asm w/ memory clobber so the compiler never emits the
// conservative vmcnt(0) drain of __syncthreads). Loads for step k+2 are
// issued right after the barrier of step k and stay in flight across the
// next barrier (AITER-style). Safety: the stage target buffer is the one
// all waves finished ds_reading one iteration ago (MFMA's lgkm drain
// guarantees ds_read completion before each wave reaches the barrier).
// Wait arithmetic: prologue = 6 inflight; per iter wait vmcnt(3) (own 3
// oldest = current buffer landed), issue 3 more; last iter waits vmcnt(0).

template <bool OUT_BF16, bool QKV_BIAS>
__global__ __launch_bounds__(256) void gemm_bt(
    const bf16* __restrict__ A, const bf16* __restrict__ Bt,
    const float* __restrict__ b0, const float* __restrict__ b1,
    const float* __restrict__ b2, void* __restrict__ Cv, bf16* __restrict__ Vt,
    int M, int N, int K, int nbx, int bands_per_xcd)
{
    __shared__ bf16 As[3][128 * 32];
    __shared__ bf16 Bs[3][64 * 32];
    const int blk = blockIdx.x;
    const int xcd = blk & 7;
    const int s   = blk >> 3;
    const int m0 = (xcd * bands_per_xcd + s / nbx) * 128;
    const int n0 = (s % nbx) * 64;
    const int tid  = threadIdx.x;
    const int wave = tid >> 6, lane = tid & 63;
    const int quad = lane >> 4, l16 = lane & 15;
    const int wm = wave >> 1, wn = wave & 1;

    f32x4 acc[4][2] = {};

    const int srow = wave * 16 + (lane >> 2);   // 0..63
    const int scol = (lane & 3) * 8;            // element offset in 32-elem row
    const bf16* ga0 = A  + (size_t)(m0 + srow) * K + scol;
    const bf16* ga1 = A  + (size_t)(m0 + srow + 64) * K + scol;
    const bf16* gb  = Bt + (size_t)(n0 + srow) * K + scol;
    const int sA0 = srow * 32 + scol;
    const int sA1 = (srow + 64) * 32 + scol;
    const int sB  = srow * 32 + scol;

    bf16 *Ac = &As[0][0], *An = &As[1][0], *Ao = &As[2][0];
    bf16 *Bc = &Bs[0][0], *Bn = &Bs[1][0], *Bo = &Bs[2][0];

    // prologue: stage kt=0 -> buf0, kt=1 -> buf1 (6 loads in flight)
    gload_lds16(ga0, Ac + sA0);
    gload_lds16(ga1, Ac + sA1);
    gload_lds16(gb,  Bc + sB);
    gload_lds16(ga0 + 32, An + sA0);
    gload_lds16(ga1 + 32, An + sA1);
    gload_lds16(gb  + 32, Bn + sB);

    const int raoff = (wm * 64 + l16) * 32 + quad * 8;
    const int rboff = (wn * 32 + l16) * 32 + quad * 8;

    const int nk = K >> 5;
    for (int kt = 0; kt < nk; ++kt) {
        if (kt + 1 < nk) asm volatile("s_waitcnt vmcnt(3)" ::: "memory");
        else             asm volatile("s_waitcnt vmcnt(0)" ::: "memory");
        asm volatile("s_barrier" ::: "memory");
        if (kt + 2 < nk) {
            gload_lds16(ga0 + (kt + 2) * 32, Ao + sA0);
            gload_lds16(ga1 + (kt + 2) * 32, Ao + sA1);
            gload_lds16(gb  + (kt + 2) * 32, Bo + sB);
        }
        bf16x8 af[4], bfr[2];
#pragma unroll
        for (int i = 0; i < 4; ++i)
            af[i] = *(const bf16x8*)(Ac + raoff + i * 16 * 32);
#pragma unroll
        for (int j = 0; j < 2; ++j)
            bfr[j] = *(const bf16x8*)(Bc + rboff + j * 16 * 32);
#pragma unroll
        for (int i = 0; i < 4; ++i)
#pragma unroll
            for (int j = 0; j < 2; ++j)
                acc[i][j] = __builtin_amdgcn_mfma_f32_16x16x32_bf16(af[i], bfr[j], acc[i][j], 0, 0, 0);
        bf16* t;
        t = Ac; Ac = An; An = Ao; Ao = t;
        t = Bc; Bc = Bn; Bn = Bo; Bo = t;
    }

    const bool vtile = QKV_BIAS && (n0 >= 1280);
#pragma unroll
    for (int i = 0; i < 4; ++i)
#pragma unroll
        for (int j = 0; j < 2; ++j) {
            const int col = n0 + wn * 32 + j * 16 + l16;
            const float bb = QKV_BIAS
                ? (col < 1024 ? b0[col] : (col < 1280 ? b1[col - 1024] : b2[col - 1280]))
                : b0[col];
            const int row0 = m0 + wm * 64 + i * 16 + quad * 4;
            if (vtile) {
                bf16x4 pv;
#pragma unroll
                for (int r = 0; r < 4; ++r) pv[r] = (bf16)(acc[i][j][r] + bb);
                *(bf16x4*)&Vt[(size_t)(col - 1280) * VT_LD + row0] = pv;
            } else {
#pragma unroll
                for (int r = 0; r < 4; ++r) {
                    const float v = acc[i][j][r] + bb;
                    if (OUT_BF16) ((bf16*)Cv)[(size_t)(row0 + r) * N + col] = (bf16)v;
                    else          ((float*)Cv)[(size_t)(row0 + r) * N + col] = v;
                }
            }
        }
}

// ---------------- attention: 4 waves/block, 1 wave per (16-query tile, head) --
// Window <= 272 keys -> 17 S tiles of 16, PV over 9 K-chunks of 32.

__global__ __launch_bounds__(256) void attn_kernel(
    const bf16* __restrict__ QKV, const bf16* __restrict__ Vt, bf16* __restrict__ Oa)
{
    __shared__ bf16 Ps[4][16][296];   // per-wave P tile; 592 B rows: 2-way alias only
    const int wave = threadIdx.x >> 6;
    const int lane = threadIdx.x & 63;
    const int q0 = (blockIdx.x * 4 + wave) * 16;
    const int h  = blockIdx.y;
    const int kh = h >> 2;                     // GQA: head h -> kv head h/4
    const int quad = lane >> 4, l16 = lane & 15;
    const float slope = exp2f(-0.5f * (float)(h + 1));   // NH=16 ALiBi slopes
    const int lo = (q0 >= 256) ? (q0 - 256) : 0;          // window start

    // Q A-fragments (k-chunks 0 and 32 of HD=64)
    const bf16* qp = QKV + (size_t)(q0 + l16) * QKV_LD + h * 64 + quad * 8;
    bf16x8 qf0 = *(const bf16x8*)qp;
    bf16x8 qf1 = *(const bf16x8*)(qp + 32);

    // S = Q K^T : 17 tiles of 16 keys, fully unrolled so s[] stays in VGPRs
    f32x4 s[17];
#pragma unroll
    for (int t = 0; t < 17; ++t) {
        const bf16* kp = QKV + (size_t)(lo + t * 16 + l16) * QKV_LD + D_MODEL + kh * 64 + quad * 8;
        bf16x8 kf0 = *(const bf16x8*)kp;
        bf16x8 kf1 = *(const bf16x8*)(kp + 32);
        f32x4 a = {};
        a = __builtin_amdgcn_mfma_f32_16x16x32_bf16(qf0, kf0, a, 0, 0, 0);
        a = __builtin_amdgcn_mfma_f32_16x16x32_bf16(qf1, kf1, a, 0, 0, 0);
        s[t] = a;
    }

    // masked ALiBi softmax; lane holds rows quad*4+r at col l16 of each tile
    float rinv[4];
#pragma unroll
    for (int r = 0; r < 4; ++r) {
        const int row = q0 + quad * 4 + r;
        float mx = -1e30f;
#pragma unroll
        for (int t = 0; t < 17; ++t) {
            const int key = lo + t * 16 + l16;
            float v = s[t][r] * 0.125f - slope * (float)(row - key);
            const bool ok = (key <= row) && (key > row - WINDOW);
            v = ok ? v : -1e30f;
            s[t][r] = v;
            mx = fmaxf(mx, v);
        }
#pragma unroll
        for (int d = 1; d < 16; d <<= 1) mx = fmaxf(mx, __shfl_xor(mx, d));
        float sum = 0.f;
#pragma unroll
        for (int t = 0; t < 17; ++t) {
            float p = __expf(s[t][r] - mx);
            s[t][r] = p;
            sum += p;
        }
#pragma unroll
        for (int d = 1; d < 16; d <<= 1) sum += __shfl_xor(sum, d);
        rinv[r] = 1.f / sum;
    }

    // zero pad cols [272,288) (PV reads 288 cols)
    {
        int idx = lane;
#pragma unroll
        for (int it = 0; it < 4; ++it) {
            Ps[wave][(idx >> 4) & 15][272 + (idx & 15)] = (bf16)0.f;
            idx += 64;
        }
    }
    // P: C-layout regs -> LDS -> A-layout frags
#pragma unroll
    for (int t = 0; t < 17; ++t)
#pragma unroll
        for (int r = 0; r < 4; ++r)
            Ps[wave][quad * 4 + r][t * 16 + l16] = (bf16)(s[t][r] * rinv[r]);
    __syncthreads();

    // O = P V : V B-frags straight from global Vt (contiguous along keys)
    f32x4 o[4] = {};
#pragma unroll
    for (int c = 0; c < 9; ++c) {
        bf16x8 pf = *(const bf16x8*)&Ps[wave][l16][c * 32 + quad * 8];
#pragma unroll
        for (int j = 0; j < 4; ++j) {
            const bf16* vp = Vt + (size_t)(kh * 64 + j * 16 + l16) * VT_LD + lo + c * 32 + quad * 8;
            bf16x8 vf = *(const bf16x8*)vp;
            o[j] = __builtin_amdgcn_mfma_f32_16x16x32_bf16(pf, vf, o[j], 0, 0, 0);
        }
    }

#pragma unroll
    for (int j = 0; j < 4; ++j)
#pragma unroll
        for (int r = 0; r < 4; ++r)
            Oa[(size_t)(q0 + quad * 4 + r) * D_MODEL + h * 64 + j * 16 + l16] = (bf16)o[j][r];
}

// ---------------- launch ----------------

extern "C" void kernel_launch(void* const* d_in, const int* in_sizes, int n_in,
                              void* d_out, int out_size, void* d_ws, size_t ws_size,
                              hipStream_t stream) {
    const float* x  = (const float*)d_in[0];
    const float* Wq = (const float*)d_in[1];
    const float* bq = (const float*)d_in[2];
    const float* Wk = (const float*)d_in[3];
    const float* bk = (const float*)d_in[4];
    const float* Wv = (const float*)d_in[5];
    const float* bv = (const float*)d_in[6];
    const float* Wo = (const float*)d_in[7];
    const float* bo = (const float*)d_in[8];
    float* out = (float*)d_out;

    char* ws = (char*)d_ws;
    bf16*  xb    = (bf16*)(ws);                    // 4096x1024 bf16   (8 MB)
    bf16*  WtQKV = (bf16*)(ws + 8388608);          // 1536x1024 bf16   (3 MB)
    bf16*  WtO   = (bf16*)(ws + 11534336);         // 1024x1024 bf16   (2 MB)
    bf16*  QKV   = (bf16*)(ws + 13637632);         // 4096x1536 bf16   (12 MB; V region unused)
    bf16*  Vt    = (bf16*)(ws + 26220544);         // 256xVT_LD bf16   (~2 MB)
    bf16*  AO    = (bf16*)(ws + 28334080);         // 4096x1024 bf16   (8 MB) -> end ~35 MB

    prep_fused<<<4608, 256, 0, stream>>>(x, Wq, Wk, Wv, Wo, xb, WtQKV, WtO);

    gemm_bt<true, true><<<768, 256, 0, stream>>>(
        xb, WtQKV, bq, bk, bv, QKV, Vt, 4096, 1536, 1024, 24, 4);

    attn_kernel<<<dim3(64, 16), 256, 0, stream>>>(QKV, Vt, AO);

    gemm_bt<false, false><<<512, 256, 0, stream>>>(
        AO, WtO, bo, nullptr, nullptr, out, nullptr, 4096, 1024, 1024, 16, 4);
}